// Round 5
// baseline (440.612 us; speedup 1.0000x reference)
//
#include <hip/hip_runtime.h>
#include <math.h>

// ============================ problem constants ============================
#define NB    128
#define NS    40
#define NW    50
#define ED    200   // = 2*HW = 2*HS
#define NHW   100
#define FEAT  200
#define NC    10
#define VOCABM1 99999
#define KL2E  1.4426950408889634f

// ============================ ws memory map (bytes) ========================
// Weight blobs pre-padded: 48 rows x 464 B (28x16B bf16 weights, K zero-padded
// to 224, + 16 B pad unit per row carrying fp32 bias/ctx constants).
#define BB       22272ull
#define OFF_PGW  0ull
#define OFF_PAW  (14ull*BB)            // 311,808
#define OFF_PGS  (OFF_PAW + 5ull*BB)   // 423,168
#define OFF_PAS  (OFF_PGS + 14ull*BB)  // 734,976
#define OFF_SV   846336ull             // svec [5120][200] bf16 = 2,048,000
#define WS_NEED  4194304ull            // also covers fp32 fallback's svec

// ============================ helpers ======================================
typedef short bf16x8 __attribute__((ext_vector_type(8)));
typedef float f32x4  __attribute__((ext_vector_type(4)));

__device__ __forceinline__ unsigned short f2bf(float f) {
    unsigned int u = __float_as_uint(f);
    u += 0x7fffu + ((u >> 16) & 1u);          // RNE
    return (unsigned short)(u >> 16);
}
__device__ __forceinline__ float bf2f(short s) {
    return __uint_as_float(((unsigned int)(unsigned short)s) << 16);
}
__device__ __forceinline__ float frcp(float x) { return __builtin_amdgcn_rcpf(x); }
#if __has_builtin(__builtin_amdgcn_exp2f)
__device__ __forceinline__ float fexp2(float x){ return __builtin_amdgcn_exp2f(x); }
#else
__device__ __forceinline__ float fexp2(float x){ return exp2f(x); }
#endif
__device__ __forceinline__ float fsig(float x) { return frcp(1.f + __expf(-x)); }
__device__ __forceinline__ float ftanh(float x){ return 1.f - 2.f*frcp(1.f + __expf(2.f*x)); }
__device__ __forceinline__ unsigned pk2(float a, float b) {
    return (unsigned)f2bf(a) | ((unsigned)f2bf(b) << 16);
}

// async global->LDS, 16B per lane; LDS dst = wave-uniform base + lane*16.
__device__ __forceinline__ void gld16(const void* g, void* l) {
    __builtin_amdgcn_global_load_lds(
        (const __attribute__((address_space(1))) void*)g,
        (__attribute__((address_space(3))) void*)l, 16, 0, 0);
}

template<int NT>
__device__ __forceinline__ void stageBlob(char* __restrict__ dst,
                                          const char* __restrict__ src, int tid)
{
    for (int t = tid; t < 1392; t += NT)
        gld16(src + (size_t)t * 16, dst + (size_t)t * 16);
}

__device__ __forceinline__ bf16x8 pack8(float4 a, float4 b) {
    bf16x8 r;
    r[0]=(short)f2bf(a.x); r[1]=(short)f2bf(a.y); r[2]=(short)f2bf(a.z); r[3]=(short)f2bf(a.w);
    r[4]=(short)f2bf(b.x); r[5]=(short)f2bf(b.y); r[6]=(short)f2bf(b.z); r[7]=(short)f2bf(b.w);
    return r;
}

__device__ __forceinline__ bf16x8 ldB(const char* buf, int rbase, int ln15, int kc, int q) {
    return *(const bf16x8*)(buf + (size_t)(rbase + ln15) * 464 + kc * 64 + q * 16);
}

// ============================ P1: weight packing ===========================
// 38 blocks: 0..13 word GRU (dir*7+c), 14..18 word attn, 19..32 sent GRU,
// 33..37 sent attn. GRU pad rows 0..15: [bR'(16) bZ'(16) bN2(16) hN2(16)],
// bR' = -K(bihR+bhhR), bZ' = K(bihZ+bhhZ), bN2 = 2K*bihN, hN2 = 2K*bhhN.
// Attn pad rows 0..11: ab2 = 2K*ab; rows 12..23: cx2n = -2*cx.
__global__ void pack_kernel(
    const float* __restrict__ wWf, const float* __restrict__ wbif, const float* __restrict__ wbhf,
    const float* __restrict__ wWb, const float* __restrict__ wbib, const float* __restrict__ wbhb,
    const float* __restrict__ waW, const float* __restrict__ wab, const float* __restrict__ wactx,
    const float* __restrict__ sWf, const float* __restrict__ sbif, const float* __restrict__ sbhf,
    const float* __restrict__ sWb, const float* __restrict__ sbib, const float* __restrict__ sbhb,
    const float* __restrict__ saW, const float* __restrict__ sab, const float* __restrict__ sactx,
    char* __restrict__ ws)
{
    const int b = blockIdx.x, tid = threadIdx.x;
    const bool word = b < 19;
    const int lb = word ? b : b - 19;
    char* blob;
    if (lb < 14) blob = ws + (word ? OFF_PGW : OFF_PGS) + (size_t)lb * BB;
    else         blob = ws + (word ? OFF_PAW : OFF_PAS) + (size_t)(lb - 14) * BB;

    for (int i = tid; i < (int)(BB / 4); i += 256) ((unsigned*)blob)[i] = 0u;
    __syncthreads();

    unsigned short* w16 = (unsigned short*)blob;
    if (lb < 14) {
        const int dir = lb / 7, c = lb % 7;
        const float* W   = word ? (dir ? wWb : wWf) : (dir ? sWb : sWf);
        const float* bih = word ? (dir ? wbib : wbif) : (dir ? sbib : sbif);
        const float* bhh = word ? (dir ? wbhb : wbhf) : (dir ? sbhb : sbhf);
        for (int e = tid; e < 48 * 200; e += 256) {
            const int row = e / 200, k = e - row * 200;
            const int gate = row >> 4, j = c * 16 + (row & 15);
            if (j < NHW) w16[row * 232 + k] = f2bf(W[(size_t)(gate * NHW + j) * ED + k]);
        }
        if (tid < 64) {
            const int sect = tid >> 4, j = c * 16 + (tid & 15);
            float v = 0.f;
            if (j < NHW) {
                if (sect == 0)      v = -KL2E * (bih[j] + bhh[j]);
                else if (sect == 1) v =  KL2E * (bih[NHW + j] + bhh[NHW + j]);
                else if (sect == 2) v = 2.f * KL2E * bih[2 * NHW + j];
                else                v = 2.f * KL2E * bhh[2 * NHW + j];
            }
            ((float*)(blob + (size_t)(tid >> 2) * 464 + 448))[tid & 3] = v;
        }
    } else {
        const int cb = lb - 14;
        const float* W  = word ? waW : saW;
        const float* ab = word ? wab : sab;
        const float* cx = word ? wactx : sactx;
        for (int e = tid; e < 48 * 200; e += 256) {
            const int row = e / 200, k = e - row * 200;
            const int d = cb * 48 + row;
            if (d < FEAT) w16[row * 232 + k] = f2bf(W[(size_t)d * FEAT + k]);
        }
        if (tid < 48) {
            const int d = cb * 48 + tid;
            float ab2 = 0.f, cxn = 0.f;
            if (d < FEAT) { ab2 = 2.f * KL2E * ab[d]; cxn = -2.f * cx[d]; }
            ((float*)(blob + (size_t)(tid >> 2) * 464 + 448))[tid & 3] = ab2;
            ((float*)(blob + (size_t)(12 + (tid >> 2)) * 464 + 448))[tid & 3] = cxn;
        }
    }
}

// ============================ word stage ===================================
// Block = 4 sentences, 256 thr = 4 waves; wave = 1 sentence, Mt=4 (64 rows).
// A-frags (emb gather, fp32->bf16 in-reg) live in registers for all 14 GRU
// chunks; B blobs double-buffered in LDS; h -> LDS H (wave-private rows);
// frag array reloaded as attention A-frags from H; scores -> shfl d-reduce ->
// per-wave softmax -> pooling from frags -> svec bf16.
__global__ __launch_bounds__(256, 1) void han_word(
    const int* __restrict__ xtok, const float* __restrict__ emb,
    const char* __restrict__ gpk, const char* __restrict__ apk,
    unsigned short* __restrict__ Out)
{
    __shared__ __align__(16) char smem[156672];
    char*  Hsh   = smem;                       // [4][64][416]
    char*  bufs  = smem + 106496;              // 2 x 22272
    float* sc_sh = (float*)(smem + 151040);    // [4][64]
    float* al_sh = (float*)(smem + 152064);    // [4][64]
    float* part  = (float*)(smem + 153088);    // [4][224]

    const int tid  = threadIdx.x;
    const int lane = tid & 63, wv = tid >> 6;
    const int ln15 = lane & 15, q = lane >> 4;
    const long g   = (long)blockIdx.x * 4 + wv;
    char* Hme = Hsh + (size_t)wv * 26624;

    // ---- A fragments from fp32 emb (4 tokens per lane) ----
    bf16x8 frag[4][7];
    #pragma unroll
    for (int Mt = 0; Mt < 4; ++Mt) {
        const int item = Mt * 16 + ln15;
        int tok = VOCABM1;                         // padding row: all zeros
        if (item < NW) tok = xtok[g * NW + item];
        const float4* rp = (const float4*)(emb + (long)tok * ED);
        #pragma unroll
        for (int kc = 0; kc < 6; ++kc)
            frag[Mt][kc] = pack8(rp[kc * 8 + q * 2], rp[kc * 8 + q * 2 + 1]);
        frag[Mt][6] = (q == 0) ? pack8(rp[48], rp[49]) : (bf16x8)(short)0;
    }

    stageBlob<256>(bufs, gpk, tid);
    __syncthreads();

    // ---------------- GRU phase: chunks 0..13 ----------------
    for (int s = 0; s < 14; ++s) {
        char* cur = bufs + (size_t)(s & 1) * BB;
        const char* nb = (s + 1 < 14) ? gpk + (size_t)(s + 1) * BB : apk;
        stageBlob<256>(bufs + (size_t)((s + 1) & 1) * BB, nb, tid);

        f32x4 a0[4] = {}, a1[4] = {}, a2[4] = {};
        #pragma unroll
        for (int kc = 0; kc < 7; ++kc) {
            const bf16x8 b0 = ldB(cur, 0,  ln15, kc, q);
            const bf16x8 b1 = ldB(cur, 16, ln15, kc, q);
            const bf16x8 b2 = ldB(cur, 32, ln15, kc, q);
            #pragma unroll
            for (int Mt = 0; Mt < 4; ++Mt) {
                a0[Mt] = __builtin_amdgcn_mfma_f32_16x16x32_bf16(b0, frag[Mt][kc], a0[Mt], 0, 0, 0);
                a1[Mt] = __builtin_amdgcn_mfma_f32_16x16x32_bf16(b1, frag[Mt][kc], a1[Mt], 0, 0, 0);
                a2[Mt] = __builtin_amdgcn_mfma_f32_16x16x32_bf16(b2, frag[Mt][kc], a2[Mt], 0, 0, 0);
            }
        }
        const int dir = s / 7, cc = s - dir * 7;
        if (cc * 16 + q * 4 < NHW) {
            const f32x4 bR = *(const f32x4*)(cur + (size_t)(0  + q) * 464 + 448);
            const f32x4 bZ = *(const f32x4*)(cur + (size_t)(4  + q) * 464 + 448);
            const f32x4 bN = *(const f32x4*)(cur + (size_t)(8  + q) * 464 + 448);
            const f32x4 hN = *(const f32x4*)(cur + (size_t)(12 + q) * 464 + 448);
            const int ub = dir * NHW + cc * 16 + q * 4;
            #pragma unroll
            for (int Mt = 0; Mt < 4; ++Mt) {
                float h[4];
                #pragma unroll
                for (int rg = 0; rg < 4; ++rg) {
                    const float r  = frcp(1.f + fexp2(fmaf(a0[Mt][rg], -KL2E, bR[rg])));
                    const float zc = frcp(1.f + fexp2(fmaf(a1[Mt][rg],  KL2E, bZ[rg])));
                    const float t  = frcp(1.f + fexp2(fmaf(a2[Mt][rg], 2.f * KL2E,
                                              fmaf(r, hN[rg], bN[rg]))));
                    h[rg] = zc * (1.f - 2.f * t);
                }
                uint2 o; o.x = pk2(h[0], h[1]); o.y = pk2(h[2], h[3]);
                *(uint2*)(Hme + (size_t)(Mt * 16 + ln15) * 416 + ub * 2) = o;
            }
        }
        __syncthreads();
    }

    // ---- reload frags as attention A-operands from LDS H ----
    #pragma unroll
    for (int Mt = 0; Mt < 4; ++Mt)
        #pragma unroll
        for (int kc = 0; kc < 7; ++kc) {
            bf16x8 v = (bf16x8)(short)0;
            if (kc < 6 || q == 0)
                v = *(const bf16x8*)(Hme + (size_t)(Mt * 16 + ln15) * 416 + kc * 64 + q * 16);
            frag[Mt][kc] = v;
        }

    // ---------------- attention phase: chunks 14..18 ----------------
    float sacc[4][4] = {{0.f}};
    for (int s = 14; s < 19; ++s) {
        char* cur = bufs + (size_t)(s & 1) * BB;
        if (s + 1 < 19)
            stageBlob<256>(bufs + (size_t)((s + 1) & 1) * BB,
                           apk + (size_t)(s + 1 - 14) * BB, tid);

        f32x4 ac[4][3] = {};
        #pragma unroll
        for (int kc = 0; kc < 7; ++kc) {
            const bf16x8 b0 = ldB(cur, 0,  ln15, kc, q);
            const bf16x8 b1 = ldB(cur, 16, ln15, kc, q);
            const bf16x8 b2 = ldB(cur, 32, ln15, kc, q);
            #pragma unroll
            for (int Mt = 0; Mt < 4; ++Mt) {
                ac[Mt][0] = __builtin_amdgcn_mfma_f32_16x16x32_bf16(frag[Mt][kc], b0, ac[Mt][0], 0, 0, 0);
                ac[Mt][1] = __builtin_amdgcn_mfma_f32_16x16x32_bf16(frag[Mt][kc], b1, ac[Mt][1], 0, 0, 0);
                ac[Mt][2] = __builtin_amdgcn_mfma_f32_16x16x32_bf16(frag[Mt][kc], b2, ac[Mt][2], 0, 0, 0);
            }
        }
        #pragma unroll
        for (int Nt = 0; Nt < 3; ++Nt) {
            const int bo = 4 * (Nt * 16 + ln15);
            const float ab2 = *(const float*)(cur + (size_t)(bo >> 4) * 464 + 448 + (bo & 15));
            const int co = 192 + bo;
            const float cxn = *(const float*)(cur + (size_t)(co >> 4) * 464 + 448 + (co & 15));
            #pragma unroll
            for (int Mt = 0; Mt < 4; ++Mt)
                #pragma unroll
                for (int rg = 0; rg < 4; ++rg) {
                    const float u = frcp(1.f + fexp2(fmaf(ac[Mt][Nt][rg], 2.f * KL2E, ab2)));
                    sacc[Mt][rg] = fmaf(u, cxn, sacc[Mt][rg]);
                }
        }
        __syncthreads();
    }

    // ---- reduce scores over the 16 d-lanes; park per row ----
    #pragma unroll
    for (int Mt = 0; Mt < 4; ++Mt)
        #pragma unroll
        for (int rg = 0; rg < 4; ++rg) {
            float v = sacc[Mt][rg];
            v += __shfl_xor(v, 1); v += __shfl_xor(v, 2);
            v += __shfl_xor(v, 4); v += __shfl_xor(v, 8);
            sacc[Mt][rg] = v;
        }
    if (ln15 == 0) {
        #pragma unroll
        for (int Mt = 0; Mt < 4; ++Mt)
            #pragma unroll
            for (int rg = 0; rg < 4; ++rg)
                sc_sh[wv * 64 + Mt * 16 + q * 4 + rg] = sacc[Mt][rg];
    }

    // ---- per-wave softmax over 64 padded rows ----
    {
        const float s0 = (lane < NW) ? sc_sh[wv * 64 + lane] : -1e30f;
        float m = s0;
        m = fmaxf(m, __shfl_xor(m, 1));  m = fmaxf(m, __shfl_xor(m, 2));
        m = fmaxf(m, __shfl_xor(m, 4));  m = fmaxf(m, __shfl_xor(m, 8));
        m = fmaxf(m, __shfl_xor(m, 16)); m = fmaxf(m, __shfl_xor(m, 32));
        const float e = (lane < NW) ? fexp2((s0 - m) * KL2E) : 0.f;
        float ss = e;
        ss += __shfl_xor(ss, 1);  ss += __shfl_xor(ss, 2);
        ss += __shfl_xor(ss, 4);  ss += __shfl_xor(ss, 8);
        ss += __shfl_xor(ss, 16); ss += __shfl_xor(ss, 32);
        al_sh[wv * 64 + lane] = e * frcp(ss);
    }

    // ---- pooling straight from frags ----
    {
        float aM[4];
        #pragma unroll
        for (int Mt = 0; Mt < 4; ++Mt) aM[Mt] = al_sh[wv * 64 + Mt * 16 + ln15];
        #pragma unroll
        for (int kc = 0; kc < 7; ++kc) {
            float p[8];
            #pragma unroll
            for (int j = 0; j < 8; ++j) {
                p[j] = aM[0] * bf2f(frag[0][kc][j]);
                #pragma unroll
                for (int Mt = 1; Mt < 4; ++Mt)
                    p[j] = fmaf(aM[Mt], bf2f(frag[Mt][kc][j]), p[j]);
            }
            #pragma unroll
            for (int j = 0; j < 8; ++j) {
                p[j] += __shfl_xor(p[j], 1); p[j] += __shfl_xor(p[j], 2);
                p[j] += __shfl_xor(p[j], 4); p[j] += __shfl_xor(p[j], 8);
            }
            if (ln15 == 0) {
                float* dst = part + (size_t)wv * 224 + kc * 32 + q * 8;
                f32x4 v0 = {p[0], p[1], p[2], p[3]};
                f32x4 v1 = {p[4], p[5], p[6], p[7]};
                *(f32x4*)dst = v0; *(f32x4*)(dst + 4) = v1;
            }
        }
    }
    __syncthreads();

    if (tid < 200) {
        const int sl = tid / 50, i = tid - sl * 50;
        const float* pa = part + (size_t)sl * 224 + i * 4;
        uint2 o;
        o.x = pk2(pa[0], pa[1]);
        o.y = pk2(pa[2], pa[3]);
        *(uint2*)(Out + ((long)blockIdx.x * 4 + sl) * 200 + i * 4) = o;
    }
}

// ============================ sentence stage + classifier ==================
// Block = 1 doc, 64 thr = 1 wave, Mt=3 (48 padded rows >= 40 sentences).
// Same pipeline as han_word, then fused FC + log_softmax writing d_out.
__global__ __launch_bounds__(64) void han_sent(
    const unsigned short* __restrict__ svec,
    const char* __restrict__ gpk, const char* __restrict__ apk,
    const float* __restrict__ fcW, const float* __restrict__ fcb,
    float* __restrict__ out)
{
    __shared__ __align__(16) char smem[66048];
    char*  Hsh   = smem;                       // [48][416] = 19,968
    char*  bufs  = smem + 19968;               // 2 x 22272
    float* sc_sh = (float*)(smem + 64512);     // [64]
    float* al_sh = (float*)(smem + 64768);     // [64]
    float* part  = (float*)(smem + 65024);     // [224]

    const int lane = threadIdx.x;
    const int ln15 = lane & 15, q = lane >> 4;
    const long doc = blockIdx.x;

    bf16x8 frag[3][7];
    #pragma unroll
    for (int Mt = 0; Mt < 3; ++Mt) {
        const int item = Mt * 16 + ln15;
        const int ic = item < NS ? item : 0;
        const char* rp = (const char*)svec + (doc * NS + ic) * 400;
        #pragma unroll
        for (int kc = 0; kc < 7; ++kc) {
            bf16x8 v = (bf16x8)(short)0;
            if (item < NS && (kc < 6 || q == 0))
                v = *(const bf16x8*)(rp + kc * 64 + q * 16);
            frag[Mt][kc] = v;
        }
    }

    stageBlob<64>(bufs, gpk, lane);
    __syncthreads();

    for (int s = 0; s < 14; ++s) {
        char* cur = bufs + (size_t)(s & 1) * BB;
        const char* nb = (s + 1 < 14) ? gpk + (size_t)(s + 1) * BB : apk;
        stageBlob<64>(bufs + (size_t)((s + 1) & 1) * BB, nb, lane);

        f32x4 a0[3] = {}, a1[3] = {}, a2[3] = {};
        #pragma unroll
        for (int kc = 0; kc < 7; ++kc) {
            const bf16x8 b0 = ldB(cur, 0,  ln15, kc, q);
            const bf16x8 b1 = ldB(cur, 16, ln15, kc, q);
            const bf16x8 b2 = ldB(cur, 32, ln15, kc, q);
            #pragma unroll
            for (int Mt = 0; Mt < 3; ++Mt) {
                a0[Mt] = __builtin_amdgcn_mfma_f32_16x16x32_bf16(b0, frag[Mt][kc], a0[Mt], 0, 0, 0);
                a1[Mt] = __builtin_amdgcn_mfma_f32_16x16x32_bf16(b1, frag[Mt][kc], a1[Mt], 0, 0, 0);
                a2[Mt] = __builtin_amdgcn_mfma_f32_16x16x32_bf16(b2, frag[Mt][kc], a2[Mt], 0, 0, 0);
            }
        }
        const int dir = s / 7, cc = s - dir * 7;
        if (cc * 16 + q * 4 < NHW) {
            const f32x4 bR = *(const f32x4*)(cur + (size_t)(0  + q) * 464 + 448);
            const f32x4 bZ = *(const f32x4*)(cur + (size_t)(4  + q) * 464 + 448);
            const f32x4 bN = *(const f32x4*)(cur + (size_t)(8  + q) * 464 + 448);
            const f32x4 hN = *(const f32x4*)(cur + (size_t)(12 + q) * 464 + 448);
            const int ub = dir * NHW + cc * 16 + q * 4;
            #pragma unroll
            for (int Mt = 0; Mt < 3; ++Mt) {
                float h[4];
                #pragma unroll
                for (int rg = 0; rg < 4; ++rg) {
                    const float r  = frcp(1.f + fexp2(fmaf(a0[Mt][rg], -KL2E, bR[rg])));
                    const float zc = frcp(1.f + fexp2(fmaf(a1[Mt][rg],  KL2E, bZ[rg])));
                    const float t  = frcp(1.f + fexp2(fmaf(a2[Mt][rg], 2.f * KL2E,
                                              fmaf(r, hN[rg], bN[rg]))));
                    h[rg] = zc * (1.f - 2.f * t);
                }
                uint2 o; o.x = pk2(h[0], h[1]); o.y = pk2(h[2], h[3]);
                *(uint2*)(Hsh + (size_t)(Mt * 16 + ln15) * 416 + ub * 2) = o;
            }
        }
        __syncthreads();
    }

    #pragma unroll
    for (int Mt = 0; Mt < 3; ++Mt)
        #pragma unroll
        for (int kc = 0; kc < 7; ++kc) {
            bf16x8 v = (bf16x8)(short)0;
            if (kc < 6 || q == 0)
                v = *(const bf16x8*)(Hsh + (size_t)(Mt * 16 + ln15) * 416 + kc * 64 + q * 16);
            frag[Mt][kc] = v;
        }

    float sacc[3][4] = {{0.f}};
    for (int s = 14; s < 19; ++s) {
        char* cur = bufs + (size_t)(s & 1) * BB;
        if (s + 1 < 19)
            stageBlob<64>(bufs + (size_t)((s + 1) & 1) * BB,
                          apk + (size_t)(s + 1 - 14) * BB, lane);

        f32x4 ac[3][3] = {};
        #pragma unroll
        for (int kc = 0; kc < 7; ++kc) {
            const bf16x8 b0 = ldB(cur, 0,  ln15, kc, q);
            const bf16x8 b1 = ldB(cur, 16, ln15, kc, q);
            const bf16x8 b2 = ldB(cur, 32, ln15, kc, q);
            #pragma unroll
            for (int Mt = 0; Mt < 3; ++Mt) {
                ac[Mt][0] = __builtin_amdgcn_mfma_f32_16x16x32_bf16(frag[Mt][kc], b0, ac[Mt][0], 0, 0, 0);
                ac[Mt][1] = __builtin_amdgcn_mfma_f32_16x16x32_bf16(frag[Mt][kc], b1, ac[Mt][1], 0, 0, 0);
                ac[Mt][2] = __builtin_amdgcn_mfma_f32_16x16x32_bf16(frag[Mt][kc], b2, ac[Mt][2], 0, 0, 0);
            }
        }
        #pragma unroll
        for (int Nt = 0; Nt < 3; ++Nt) {
            const int bo = 4 * (Nt * 16 + ln15);
            const float ab2 = *(const float*)(cur + (size_t)(bo >> 4) * 464 + 448 + (bo & 15));
            const int co = 192 + bo;
            const float cxn = *(const float*)(cur + (size_t)(co >> 4) * 464 + 448 + (co & 15));
            #pragma unroll
            for (int Mt = 0; Mt < 3; ++Mt)
                #pragma unroll
                for (int rg = 0; rg < 4; ++rg) {
                    const float u = frcp(1.f + fexp2(fmaf(ac[Mt][Nt][rg], 2.f * KL2E, ab2)));
                    sacc[Mt][rg] = fmaf(u, cxn, sacc[Mt][rg]);
                }
        }
        __syncthreads();
    }

    #pragma unroll
    for (int Mt = 0; Mt < 3; ++Mt)
        #pragma unroll
        for (int rg = 0; rg < 4; ++rg) {
            float v = sacc[Mt][rg];
            v += __shfl_xor(v, 1); v += __shfl_xor(v, 2);
            v += __shfl_xor(v, 4); v += __shfl_xor(v, 8);
            sacc[Mt][rg] = v;
        }
    if (ln15 == 0) {
        #pragma unroll
        for (int Mt = 0; Mt < 3; ++Mt)
            #pragma unroll
            for (int rg = 0; rg < 4; ++rg)
                sc_sh[Mt * 16 + q * 4 + rg] = sacc[Mt][rg];
    }
    __syncthreads();

    {
        const float s0 = (lane < NS) ? sc_sh[lane] : -1e30f;
        float m = s0;
        m = fmaxf(m, __shfl_xor(m, 1));  m = fmaxf(m, __shfl_xor(m, 2));
        m = fmaxf(m, __shfl_xor(m, 4));  m = fmaxf(m, __shfl_xor(m, 8));
        m = fmaxf(m, __shfl_xor(m, 16)); m = fmaxf(m, __shfl_xor(m, 32));
        const float e = (lane < NS) ? fexp2((s0 - m) * KL2E) : 0.f;
        float ss = e;
        ss += __shfl_xor(ss, 1);  ss += __shfl_xor(ss, 2);
        ss += __shfl_xor(ss, 4);  ss += __shfl_xor(ss, 8);
        ss += __shfl_xor(ss, 16); ss += __shfl_xor(ss, 32);
        al_sh[lane] = e * frcp(ss);
    }
    __syncthreads();

    {
        float aM[3];
        #pragma unroll
        for (int Mt = 0; Mt < 3; ++Mt) aM[Mt] = al_sh[Mt * 16 + ln15];
        #pragma unroll
        for (int kc = 0; kc < 7; ++kc) {
            float p[8];
            #pragma unroll
            for (int j = 0; j < 8; ++j) {
                p[j] = aM[0] * bf2f(frag[0][kc][j]);
                p[j] = fmaf(aM[1], bf2f(frag[1][kc][j]), p[j]);
                p[j] = fmaf(aM[2], bf2f(frag[2][kc][j]), p[j]);
            }
            #pragma unroll
            for (int j = 0; j < 8; ++j) {
                p[j] += __shfl_xor(p[j], 1); p[j] += __shfl_xor(p[j], 2);
                p[j] += __shfl_xor(p[j], 4); p[j] += __shfl_xor(p[j], 8);
            }
            if (ln15 == 0) {
                float* dst = part + kc * 32 + q * 8;
                f32x4 v0 = {p[0], p[1], p[2], p[3]};
                f32x4 v1 = {p[4], p[5], p[6], p[7]};
                *(f32x4*)dst = v0; *(f32x4*)(dst + 4) = v1;
            }
        }
    }
    __syncthreads();

    // ---- fused classifier + log_softmax ----
    {
        const int c = ln15;
        float acc = (q == 0 && c < NC) ? fcb[c] : 0.f;
        #pragma unroll 10
        for (int i = 0; i < 50; ++i) {
            const int k = q * 50 + i;
            const float w = (c < NC) ? fcW[c * FEAT + k] : 0.f;
            acc = fmaf(w, part[k], acc);
        }
        acc += __shfl_xor(acc, 16); acc += __shfl_xor(acc, 32);
        const float lg = (c < NC) ? acc : -1e30f;
        float m = lg;
        m = fmaxf(m, __shfl_xor(m, 1)); m = fmaxf(m, __shfl_xor(m, 2));
        m = fmaxf(m, __shfl_xor(m, 4)); m = fmaxf(m, __shfl_xor(m, 8));
        const float e = (c < NC) ? __expf(lg - m) : 0.f;
        float ss = e;
        ss += __shfl_xor(ss, 1); ss += __shfl_xor(ss, 2);
        ss += __shfl_xor(ss, 4); ss += __shfl_xor(ss, 8);
        const float lse = m + __logf(ss);
        if (lane < NC) out[doc * NC + lane] = lg - lse;
    }
}

// ======================================================================
// Fallback fp32 path — used only if ws_size < WS_NEED.
// ======================================================================
template<int NWRD, int WT>
__device__ __forceinline__ void encode_block(
    float* __restrict__ e_sh, float* __restrict__ h_sh, float* __restrict__ sc_sh,
    const float* __restrict__ Wf, const float* __restrict__ bihf, const float* __restrict__ bhhf,
    const float* __restrict__ Wb, const float* __restrict__ bihb, const float* __restrict__ bhhb,
    const float* __restrict__ aW, const float* __restrict__ ab, const float* __restrict__ actx,
    int tid)
{
    constexpr int WG = NWRD / WT;
    for (int item = tid; item < FEAT * WG; item += 256) {
        const int unit = item % FEAT, wg = item / FEAT;
        const int dir = unit / NHW, j = unit - dir * NHW;
        const float* Wd  = dir ? Wb : Wf;
        const float* bih = dir ? bihb : bihf;
        const float* bhh = dir ? bhhb : bhhf;
        const float4* rowR = (const float4*)(Wd + (size_t)j * ED);
        const float4* rowZ = (const float4*)(Wd + (size_t)(NHW + j) * ED);
        const float4* rowN = (const float4*)(Wd + (size_t)(2 * NHW + j) * ED);
        float aR[WT], aZ[WT], aN[WT];
        #pragma unroll
        for (int t = 0; t < WT; ++t) { aR[t] = 0.f; aZ[t] = 0.f; aN[t] = 0.f; }
        const int w0 = wg * WT;
        #pragma unroll 1
        for (int k4 = 0; k4 < ED / 4; ++k4) {
            const float4 wr = rowR[k4], wz = rowZ[k4], wn = rowN[k4];
            #pragma unroll
            for (int t = 0; t < WT; ++t) {
                const float4 e = *(const float4*)(e_sh + (w0 + t) * ED + k4 * 4);
                aR[t] += wr.x*e.x + wr.y*e.y + wr.z*e.z + wr.w*e.w;
                aZ[t] += wz.x*e.x + wz.y*e.y + wz.z*e.z + wz.w*e.w;
                aN[t] += wn.x*e.x + wn.y*e.y + wn.z*e.z + wn.w*e.w;
            }
        }
        const float bR = bih[j] + bhh[j], bZ = bih[NHW+j] + bhh[NHW+j];
        const float bN = bih[2*NHW+j], hN = bhh[2*NHW+j];
        #pragma unroll
        for (int t = 0; t < WT; ++t) {
            const float r = fsig(aR[t] + bR), z = fsig(aZ[t] + bZ);
            const float n = ftanh(aN[t] + bN + r * hN);
            h_sh[(w0 + t) * FEAT + unit] = (1.f - z) * n;
        }
    }
    __syncthreads();
    for (int item = tid; item < FEAT * WG; item += 256) {
        const int d = item % FEAT, wg = item / FEAT;
        const float4* row = (const float4*)(aW + (size_t)d * FEAT);
        float acc[WT];
        #pragma unroll
        for (int t = 0; t < WT; ++t) acc[t] = 0.f;
        const int w0 = wg * WT;
        #pragma unroll 1
        for (int k4 = 0; k4 < FEAT / 4; ++k4) {
            const float4 wv = row[k4];
            #pragma unroll
            for (int t = 0; t < WT; ++t) {
                const float4 h = *(const float4*)(h_sh + (w0 + t) * FEAT + k4 * 4);
                acc[t] += wv.x*h.x + wv.y*h.y + wv.z*h.z + wv.w*h.w;
            }
        }
        const float bb = ab[d], cc = actx[d];
        #pragma unroll
        for (int t = 0; t < WT; ++t)
            e_sh[d * NWRD + (w0 + t)] = ftanh(acc[t] + bb) * cc;
    }
    __syncthreads();
    if (tid < NWRD) {
        float s = 0.f;
        for (int d = 0; d < FEAT; ++d) s += e_sh[d * NWRD + tid];
        sc_sh[tid] = s;
    }
    __syncthreads();
    if (tid == 0) {
        float m = -1e30f;
        for (int w = 0; w < NWRD; ++w) m = fmaxf(m, sc_sh[w]);
        float s = 0.f;
        for (int w = 0; w < NWRD; ++w) { const float ev = __expf(sc_sh[w] - m); sc_sh[w] = ev; s += ev; }
        const float inv = 1.f / s;
        for (int w = 0; w < NWRD; ++w) sc_sh[w] *= inv;
    }
    __syncthreads();
}

__global__ __launch_bounds__(256) void word_kernel_f32(
    const int* __restrict__ x, const float* __restrict__ emb,
    const float* __restrict__ Wf, const float* __restrict__ bihf, const float* __restrict__ bhhf,
    const float* __restrict__ Wb, const float* __restrict__ bihb, const float* __restrict__ bhhb,
    const float* __restrict__ waW, const float* __restrict__ wab, const float* __restrict__ wactx,
    float* __restrict__ svec)
{
    __shared__ __align__(16) float e_sh[NW * ED];
    __shared__ __align__(16) float h_sh[NW * FEAT];
    __shared__ float sc_sh[NW];
    const int sent = blockIdx.x, tid = threadIdx.x;
    const int* xr = x + (size_t)sent * NW;
    for (int i = tid * 4; i < NW * ED; i += 256 * 4) {
        const int w = i / ED, k = i - w * ED;
        *(float4*)(e_sh + i) = *(const float4*)(emb + (size_t)xr[w] * ED + k);
    }
    __syncthreads();
    encode_block<NW, 25>(e_sh, h_sh, sc_sh, Wf, bihf, bhhf, Wb, bihb, bhhb, waW, wab, wactx, tid);
    if (tid < FEAT) {
        float a = 0.f;
        #pragma unroll 1
        for (int w = 0; w < NW; ++w) a += sc_sh[w] * h_sh[w * FEAT + tid];
        svec[(size_t)sent * FEAT + tid] = a;
    }
}

__global__ __launch_bounds__(256) void sent_kernel_f32(
    const float* __restrict__ svec,
    const float* __restrict__ Wf, const float* __restrict__ bihf, const float* __restrict__ bhhf,
    const float* __restrict__ Wb, const float* __restrict__ bihb, const float* __restrict__ bhhb,
    const float* __restrict__ saW, const float* __restrict__ sab, const float* __restrict__ sactx,
    const float* __restrict__ fcW, const float* __restrict__ fcb,
    float* __restrict__ out)
{
    __shared__ __align__(16) float e_sh[NS * ED];
    __shared__ __align__(16) float h_sh[NS * FEAT];
    __shared__ float sc_sh[NS];
    __shared__ float dvec_sh[FEAT];
    __shared__ float logit_sh[NC];
    __shared__ float lse_sh;
    const int b = blockIdx.x, tid = threadIdx.x;
    const float* src = svec + (size_t)b * NS * FEAT;
    for (int i = tid * 4; i < NS * FEAT; i += 256 * 4)
        *(float4*)(e_sh + i) = *(const float4*)(src + i);
    __syncthreads();
    encode_block<NS, 20>(e_sh, h_sh, sc_sh, Wf, bihf, bhhf, Wb, bihb, bhhb, saW, sab, sactx, tid);
    if (tid < FEAT) {
        float a = 0.f;
        #pragma unroll 1
        for (int s = 0; s < NS; ++s) a += sc_sh[s] * h_sh[s * FEAT + tid];
        dvec_sh[tid] = a;
    }
    __syncthreads();
    if (tid < NC) {
        float a = fcb[tid];
        const float* row = fcW + (size_t)tid * FEAT;
        for (int k = 0; k < FEAT; ++k) a += row[k] * dvec_sh[k];
        logit_sh[tid] = a;
    }
    __syncthreads();
    if (tid == 0) {
        float m = -1e30f;
        for (int c = 0; c < NC; ++c) m = fmaxf(m, logit_sh[c]);
        float s = 0.f;
        for (int c = 0; c < NC; ++c) s += __expf(logit_sh[c] - m);
        lse_sh = m + logf(s);
    }
    __syncthreads();
    if (tid < NC) out[(size_t)b * NC + tid] = logit_sh[tid] - lse_sh;
}

// ============================ launch =======================================
extern "C" void kernel_launch(void* const* d_in, const int* in_sizes, int n_in,
                              void* d_out, int out_size, void* d_ws, size_t ws_size,
                              hipStream_t stream)
{
    const int*   x     = (const int*)d_in[0];
    const float* emb   = (const float*)d_in[1];
    const float* wWf   = (const float*)d_in[2];
    const float* wbif  = (const float*)d_in[3];
    const float* wbhf  = (const float*)d_in[4];
    const float* wWb   = (const float*)d_in[5];
    const float* wbib  = (const float*)d_in[6];
    const float* wbhb  = (const float*)d_in[7];
    const float* waW   = (const float*)d_in[8];
    const float* wab   = (const float*)d_in[9];
    const float* wactx = (const float*)d_in[10];
    const float* sWf   = (const float*)d_in[11];
    const float* sbif  = (const float*)d_in[12];
    const float* sbhf  = (const float*)d_in[13];
    const float* sWb   = (const float*)d_in[14];
    const float* sbib  = (const float*)d_in[15];
    const float* sbhb  = (const float*)d_in[16];
    const float* saW   = (const float*)d_in[17];
    const float* sab   = (const float*)d_in[18];
    const float* sactx = (const float*)d_in[19];
    const float* fcW   = (const float*)d_in[20];
    const float* fcb   = (const float*)d_in[21];
    float* out = (float*)d_out;

    if (ws_size < WS_NEED) {
        float* svec = (float*)d_ws;
        word_kernel_f32<<<NB * NS, 256, 0, stream>>>(
            x, emb, wWf, wbif, wbhf, wWb, wbib, wbhb, waW, wab, wactx, svec);
        sent_kernel_f32<<<NB, 256, 0, stream>>>(
            svec, sWf, sbif, sbhf, sWb, sbib, sbhb, saW, sab, sactx, fcW, fcb, out);
        return;
    }

    char* ws = (char*)d_ws;
    unsigned short* svec = (unsigned short*)(ws + OFF_SV);

    pack_kernel<<<38, 256, 0, stream>>>(
        wWf, wbif, wbhf, wWb, wbib, wbhb, waW, wab, wactx,
        sWf, sbif, sbhf, sWb, sbib, sbhb, saW, sab, sactx, ws);

    han_word<<<NB * NS / 4, 256, 0, stream>>>(
        x, emb, ws + OFF_PGW, ws + OFF_PAW, svec);

    han_sent<<<NB, 64, 0, stream>>>(
        svec, ws + OFF_PGS, ws + OFF_PAS, fcW, fcb, out);
}